// Round 4
// baseline (497.304 us; speedup 1.0000x reference)
//
#include <hip/hip_runtime.h>
#include <math.h>

// ---------------------------------------------------------------------------
// GCN: 3 layers (128->32->32->32), radix-bucketed CSR build, fused agg+GEMM,
// readout + MLP head.
// Algebra: agg[g] = tanh( dis[g] * ( sum_{e:dst=g} hps[src_e] + hps[g] ) + b )
//          where hps = dis ⊙ (h @ W).
// Layers 2/3's GEMM is fused into the previous agg's epilogue (each 32-lane
// group holds the whole 32-wide h row -> shfl broadcast + W in LDS).
// ---------------------------------------------------------------------------

#define NBK_MAX 128
#define LCAP 32

// ---- pass A: partition edges into dst-range buckets (1024 nodes/bucket) ----
// LDS-staged appends, flushed in 8-pair (64B) quanta -> full-line writebacks.
__global__ void k_part(const int* __restrict__ src, const int* __restrict__ dst,
                       uint2* __restrict__ pairs, int* __restrict__ gcnt,
                       int E, int NB, int CAP) {
    __shared__ uint2 buf[NBK_MAX][LCAP];
    __shared__ int lcnt[NBK_MAX];
    int tid = threadIdx.x;
    for (int b = tid; b < NB; b += 256) lcnt[b] = 0;
    __syncthreads();
    int ntiles = (E + 255) / 256;
    for (int tile = blockIdx.x; tile < ntiles; tile += gridDim.x) {
        int e = tile * 256 + tid;
        if (e < E) {
            int s = src[e], d = dst[e];
            int b = d >> 10;
            int li = atomicAdd(&lcnt[b], 1);
            if (li < LCAP) {
                buf[b][li] = make_uint2((unsigned)s, (unsigned)d);
            } else {              // rare overflow: direct scattered append
                int gp = atomicAdd(&gcnt[b], 1);
                if (gp < CAP) pairs[(size_t)b * CAP + gp] = make_uint2((unsigned)s, (unsigned)d);
            }
        }
        __syncthreads();
        if (tid < NB) {
            int c = lcnt[tid]; if (c > LCAP) c = LCAP;
            int m = c & ~7;
            if (m) {
                int base = atomicAdd(&gcnt[tid], m);
                uint2* dp = &pairs[(size_t)tid * CAP + base];
                for (int i = 0; i < m; ++i) dp[i] = buf[tid][i];
                for (int i = m; i < c; ++i) buf[tid][i - m] = buf[tid][i];
            }
            lcnt[tid] = c - m;
        }
        __syncthreads();
    }
    // final drain (partial lines, small volume)
    if (tid < NB) {
        int c = lcnt[tid]; if (c > LCAP) c = LCAP;
        if (c) {
            int base = atomicAdd(&gcnt[tid], c);
            uint2* dp = &pairs[(size_t)tid * CAP + base];
            for (int i = 0; i < c; ++i) dp[i] = buf[tid][i];
        }
    }
}

// ---- count in-degree from bucketed pairs (atomics are bucket-local) ----
__global__ void k_count(const uint2* __restrict__ pairs, const int* __restrict__ gcnt,
                        int* __restrict__ cnt, int CAP, int C) {
    int b = blockIdx.x / C, sub = blockIdx.x % C;
    int nb = gcnt[b]; if (nb > CAP) nb = CAP;
    for (int i = sub * 256 + threadIdx.x; i < nb; i += C * 256)
        atomicAdd(&cnt[pairs[(size_t)b * CAP + i].y], 1);
}

// ---- scan (rowptr) + dis fused ----
__global__ void k_scan1(const int* __restrict__ cnt, int* __restrict__ rowptr,
                        int* __restrict__ partials, float* __restrict__ dis, int n) {
    __shared__ int s[256];
    int i = blockIdx.x * 256 + threadIdx.x;
    int v = (i < n) ? cnt[i] : 0;
    if (i < n) dis[i] = rsqrtf(1.0f + (float)v);
    s[threadIdx.x] = v;
    __syncthreads();
    for (int off = 1; off < 256; off <<= 1) {
        int t = (threadIdx.x >= off) ? s[threadIdx.x - off] : 0;
        __syncthreads();
        s[threadIdx.x] += t;
        __syncthreads();
    }
    if (i < n) rowptr[i + 1] = s[threadIdx.x];
    if (threadIdx.x == 255) partials[blockIdx.x] = s[255];
}

__global__ void k_scan2(int* __restrict__ partials, int nb) {
    __shared__ int s[512];
    int t = threadIdx.x;
    s[t] = (t < nb) ? partials[t] : 0;
    __syncthreads();
    for (int off = 1; off < 512; off <<= 1) {
        int v = (t >= off) ? s[t - off] : 0;
        __syncthreads();
        s[t] += v;
        __syncthreads();
    }
    if (t < nb) partials[t] = (t == 0) ? 0 : s[t - 1];
}

__global__ void k_scan3(int* __restrict__ rowptr, const int* __restrict__ partials, int n) {
    int i = blockIdx.x * 256 + threadIdx.x;
    if (i < n) rowptr[i + 1] += partials[blockIdx.x];
    if (i == 0) rowptr[0] = 0;
}

// ---- fill CSR from bucketed pairs (csr span per bucket ~64KB, L2-local) ----
__global__ void k_fill(const uint2* __restrict__ pairs, const int* __restrict__ gcnt,
                       int* __restrict__ cursor, int* __restrict__ csr_src,
                       int CAP, int C) {
    int b = blockIdx.x / C, sub = blockIdx.x % C;
    int nb = gcnt[b]; if (nb > CAP) nb = CAP;
    for (int i = sub * 256 + threadIdx.x; i < nb; i += C * 256) {
        uint2 p = pairs[(size_t)b * CAP + i];
        int pos = atomicAdd(&cursor[p.y], 1);
        csr_src[pos] = (int)p.x;
    }
}

// ---- layer-1 GEMM: hps[n,32] = dis ⊙ (x[n,128] @ W[128,32]) ----
// 128 threads, 64 rows/block, register 4x4 tile, W+h staged in LDS.
__global__ void k_gemm1(const float* __restrict__ h, const float* __restrict__ W,
                        const float* __restrict__ dis, float* __restrict__ hps, int n) {
    __shared__ float sW[128 * 32];          // [k][col]
    __shared__ float sh[64 * 132];          // [row][k], pad 132
    int tid = threadIdx.x;
    int row0 = blockIdx.x * 64;
    // stage W: 1024 float4
    for (int j = tid; j < 1024; j += 128)
        *(float4*)&sW[j * 4] = *(const float4*)&W[j * 4];
    // stage h: 2048 float4 (64 rows x 32 float4)
    for (int j = tid; j < 2048; j += 128) {
        int r = j >> 5, c4 = j & 31;
        float4 v = make_float4(0.f, 0.f, 0.f, 0.f);
        if (row0 + r < n) v = *(const float4*)&h[(size_t)(row0 + r) * 128 + c4 * 4];
        *(float4*)&sh[r * 132 + c4 * 4] = v;
    }
    __syncthreads();
    int rg = tid >> 3;      // 0..15 -> 4 rows each
    int cg = tid & 7;       // 0..7  -> 4 cols each
    float acc[4][4] = {};
    const float* shp = &sh[(rg * 4) * 132];
    const float* swp = &sW[cg * 4];
#pragma unroll 8
    for (int k4 = 0; k4 < 32; ++k4) {
        float4 hv0 = *(const float4*)&shp[0 * 132 + k4 * 4];
        float4 hv1 = *(const float4*)&shp[1 * 132 + k4 * 4];
        float4 hv2 = *(const float4*)&shp[2 * 132 + k4 * 4];
        float4 hv3 = *(const float4*)&shp[3 * 132 + k4 * 4];
        float4 wv0 = *(const float4*)&swp[(k4 * 4 + 0) * 32];
        float4 wv1 = *(const float4*)&swp[(k4 * 4 + 1) * 32];
        float4 wv2 = *(const float4*)&swp[(k4 * 4 + 2) * 32];
        float4 wv3 = *(const float4*)&swp[(k4 * 4 + 3) * 32];
        const float4 hv[4] = {hv0, hv1, hv2, hv3};
        const float4 wv[4] = {wv0, wv1, wv2, wv3};
#pragma unroll
        for (int r = 0; r < 4; ++r) {
            const float hr[4] = {hv[r].x, hv[r].y, hv[r].z, hv[r].w};
#pragma unroll
            for (int t = 0; t < 4; ++t) {
                acc[r][0] += hr[t] * wv[t].x;
                acc[r][1] += hr[t] * wv[t].y;
                acc[r][2] += hr[t] * wv[t].z;
                acc[r][3] += hr[t] * wv[t].w;
            }
        }
    }
#pragma unroll
    for (int r = 0; r < 4; ++r) {
        int row = row0 + rg * 4 + r;
        if (row < n) {
            float dv = dis[row];
            float4 o = make_float4(acc[r][0] * dv, acc[r][1] * dv,
                                   acc[r][2] * dv, acc[r][3] * dv);
            *(float4*)&hps[(size_t)row * 32 + cg * 4] = o;
        }
    }
}

// ---- aggregation (+ optional fused next-layer GEMM epilogue) ----
template <bool FUSE>
__global__ void k_agg(const float* __restrict__ hps, const int* __restrict__ rowptr,
                      const int* __restrict__ csr_src, const float* __restrict__ dis,
                      const float* __restrict__ bias, float* __restrict__ outc,
                      int n, const float* __restrict__ Wn, float* __restrict__ hpsn) {
    __shared__ float sW[32 * 32];
    if (FUSE) {
        for (int i = threadIdx.x; i < 1024; i += 256) sW[i] = Wn[i];
        __syncthreads();
    }
    int g    = (blockIdx.x * blockDim.x + threadIdx.x) >> 5;
    int lane = threadIdx.x & 31;
    if (g >= n) return;
    float acc = hps[(size_t)g * 32 + lane];   // self term
    int e0 = rowptr[g], e1 = rowptr[g + 1];
    int e = e0;
    for (; e + 1 < e1; e += 2) {
        int s0 = csr_src[e];
        int s1 = csr_src[e + 1];
        acc += hps[(size_t)s0 * 32 + lane] + hps[(size_t)s1 * 32 + lane];
    }
    if (e < e1) acc += hps[(size_t)csr_src[e] * 32 + lane];
    float dg = dis[g];
    float v = tanhf(dg * acc + bias[lane]);
    outc[(size_t)g * 96 + lane] = v;
    if (FUSE) {
        float a2 = 0.0f;
#pragma unroll
        for (int k = 0; k < 32; ++k)
            a2 += __shfl(v, k, 32) * sW[k * 32 + lane];
        hpsn[(size_t)g * 32 + lane] = dg * a2;
    }
}

__global__ void k_idx(const int* __restrict__ batch, int* __restrict__ idx, int n, int g) {
    int i = blockIdx.x * blockDim.x + threadIdx.x;
    if (i >= g) return;
    int lo = 0, hi = n;
    while (lo < hi) {
        int mid = (lo + hi) >> 1;
        if (batch[mid] < i) lo = mid + 1; else hi = mid;
    }
    idx[i] = lo;
}

__global__ void k_head(const float* __restrict__ cat, const int* __restrict__ idx,
                       const float* __restrict__ w1, const float* __restrict__ b1,
                       const float* __restrict__ w2, const float* __restrict__ b2,
                       float* __restrict__ out) {
    __shared__ float gv[96];
    __shared__ float s0[128];
    __shared__ float s1[128];
    int g = blockIdx.x, t = threadIdx.x;
    int node = idx[g];
    if (t < 96) gv[t] = cat[(size_t)node * 96 + t];
    __syncthreads();
    float acc = b1[t];
#pragma unroll 8
    for (int i = 0; i < 96; ++i) acc += gv[i] * w1[i * 128 + t];
    float h = fmaxf(acc, 0.0f);
    s0[t] = h * w2[t * 2 + 0];
    s1[t] = h * w2[t * 2 + 1];
    __syncthreads();
    for (int off = 64; off > 0; off >>= 1) {
        if (t < off) { s0[t] += s0[t + off]; s1[t] += s1[t + off]; }
        __syncthreads();
    }
    if (t == 0) {
        float l0 = s0[0] + b2[0];
        float l1 = s1[0] + b2[1];
        float m  = fmaxf(l0, l1);
        float lse = m + logf(expf(l0 - m) + expf(l1 - m));
        out[(size_t)g * 2 + 0] = l0 - lse;
        out[(size_t)g * 2 + 1] = l1 - lse;
    }
}

extern "C" void kernel_launch(void* const* d_in, const int* in_sizes, int n_in,
                              void* d_out, int out_size, void* d_ws, size_t ws_size,
                              hipStream_t stream) {
    const float* x    = (const float*)d_in[0];
    const int*   ei   = (const int*)d_in[1];
    const int*   batch= (const int*)d_in[2];
    const float* W1   = (const float*)d_in[4];
    const float* b1   = (const float*)d_in[5];
    const float* W2   = (const float*)d_in[6];
    const float* b2   = (const float*)d_in[7];
    const float* W3   = (const float*)d_in[8];
    const float* b3   = (const float*)d_in[9];
    const float* l1w  = (const float*)d_in[10];
    const float* l1b  = (const float*)d_in[11];
    const float* l2w  = (const float*)d_in[12];
    const float* l2b  = (const float*)d_in[13];
    float* out = (float*)d_out;

    const int N = in_sizes[0] / 128;
    const int E = in_sizes[1] / 2;
    const int G = out_size / 2;
    const int* src = ei;
    const int* dst = ei + E;

    const int NB  = (N + 1023) >> 10;      // dst buckets (1024 nodes each)
    const int CAP = 24576;                 // pairs capacity per bucket
    const int C   = 8;                     // blocks per bucket in count/fill

    char* w = (char*)d_ws;
    auto alloc = [&](size_t bytes) {
        char* p = w;
        w += (bytes + 255) & ~(size_t)255;
        return p;
    };
    int*   cnt      = (int*)  alloc((size_t)N * 4);
    float* dis      = (float*)alloc((size_t)N * 4);
    int*   rowptr   = (int*)  alloc((size_t)(N + 1) * 4);
    int*   cursor   = (int*)  alloc((size_t)N * 4);
    int*   partials = (int*)  alloc(((size_t)(N + 255) / 256) * 4);
    int*   csr_src  = (int*)  alloc((size_t)E * 4);
    uint2* pairs    = (uint2*)alloc((size_t)NB * CAP * 8);
    int*   gcnt     = (int*)  alloc((size_t)NB * 4);
    float* hpsA     = (float*)alloc((size_t)N * 32 * 4);
    float* hpsB     = (float*)alloc((size_t)N * 32 * 4);
    float* catb     = (float*)alloc((size_t)N * 96 * 4);
    int*   idx      = (int*)  alloc((size_t)G * 4);

    const int nb       = (N + 255) / 256;        // scan blocks
    const int nodes_bl = (N * 32 + 255) / 256;   // 8 nodes per 256-thr block
    const int gemm_bl  = (N + 63) / 64;

    hipMemsetAsync(cnt,  0, (size_t)N * 4, stream);
    hipMemsetAsync(gcnt, 0, (size_t)NB * 4, stream);

    k_part<<<256, 256, 0, stream>>>(src, dst, pairs, gcnt, E, NB, CAP);
    k_count<<<NB * C, 256, 0, stream>>>(pairs, gcnt, cnt, CAP, C);
    k_scan1<<<nb, 256, 0, stream>>>(cnt, rowptr, partials, dis, N);
    k_scan2<<<1, 512, 0, stream>>>(partials, nb);
    k_scan3<<<nb, 256, 0, stream>>>(rowptr, partials, N);
    hipMemcpyAsync(cursor, rowptr, (size_t)N * 4, hipMemcpyDeviceToDevice, stream);
    k_fill<<<NB * C, 256, 0, stream>>>(pairs, gcnt, cursor, csr_src, CAP, C);

    // layer 1 GEMM, then agg layers (2/3 GEMMs fused into agg epilogues)
    k_gemm1<<<gemm_bl, 128, 0, stream>>>(x, W1, dis, hpsA, N);
    k_agg<true ><<<nodes_bl, 256, 0, stream>>>(hpsA, rowptr, csr_src, dis, b1, catb + 0,  N, W2, hpsB);
    k_agg<true ><<<nodes_bl, 256, 0, stream>>>(hpsB, rowptr, csr_src, dis, b2, catb + 32, N, W3, hpsA);
    k_agg<false><<<nodes_bl, 256, 0, stream>>>(hpsA, rowptr, csr_src, dis, b3, catb + 64, N, nullptr, nullptr);

    k_idx<<<(G + 255) / 256, 256, 0, stream>>>(batch, idx, N, G);
    k_head<<<G, 128, 0, stream>>>(catb, idx, l1w, l1b, l2w, l2b, out);
}

// Round 5
// 426.207 us; speedup vs baseline: 1.1668x; 1.1668x over previous
//
#include <hip/hip_runtime.h>
#include <math.h>

// ---------------------------------------------------------------------------
// GCN: 3 layers (128->32->32->32), XCD-bucketed CSR build (nt streaming loads),
// fused agg+GEMM, readout + MLP head.
// Algebra: agg[g] = tanh( dis[g] * ( sum_{e:dst=g} hps[src_e] + hps[g] ) + b )
//          where hps = dis ⊙ (h @ W).
// CSR build: blockIdx&7 selects a dst-range bucket (~1 XCD). Each XCD's csr
// slice (~800KB) fits its 4MB L2; nontemporal loads keep the streaming edge
// scan from evicting the partially-written csr lines -> full-line writebacks.
// ---------------------------------------------------------------------------

typedef int   int4v   __attribute__((ext_vector_type(4)));
typedef float float4v __attribute__((ext_vector_type(4)));

__global__ void k_count(const int* __restrict__ dst, int* __restrict__ cnt,
                        int E, int N) {
    int q  = blockIdx.x & 7;
    int r  = blockIdx.x >> 3;
    int nb = gridDim.x >> 3;
    int lo = (int)(((long long)q * N) / 8);
    int hi = (int)(((long long)(q + 1) * N) / 8);
    const int4v* d4 = (const int4v*)dst;
    int nv = E >> 2;
    for (int i = r * blockDim.x + threadIdx.x; i < nv; i += nb * blockDim.x) {
        int4v d = __builtin_nontemporal_load(&d4[i]);
#pragma unroll
        for (int j = 0; j < 4; ++j) {
            int dd = d[j];
            if (dd >= lo && dd < hi) atomicAdd(&cnt[dd], 1);
        }
    }
    if (r == 0) {
        for (int e = (nv << 2) + threadIdx.x; e < E; e += blockDim.x) {
            int dd = dst[e];
            if (dd >= lo && dd < hi) atomicAdd(&cnt[dd], 1);
        }
    }
}

// ---- scan (rowptr) + dis fused ----
__global__ void k_scan1(const int* __restrict__ cnt, int* __restrict__ rowptr,
                        int* __restrict__ partials, float* __restrict__ dis, int n) {
    __shared__ int s[256];
    int i = blockIdx.x * 256 + threadIdx.x;
    int v = (i < n) ? cnt[i] : 0;
    if (i < n) dis[i] = rsqrtf(1.0f + (float)v);
    s[threadIdx.x] = v;
    __syncthreads();
    for (int off = 1; off < 256; off <<= 1) {
        int t = (threadIdx.x >= off) ? s[threadIdx.x - off] : 0;
        __syncthreads();
        s[threadIdx.x] += t;
        __syncthreads();
    }
    if (i < n) rowptr[i + 1] = s[threadIdx.x];
    if (threadIdx.x == 255) partials[blockIdx.x] = s[255];
}

__global__ void k_scan2(int* __restrict__ partials, int nb) {
    __shared__ int s[512];
    int t = threadIdx.x;
    s[t] = (t < nb) ? partials[t] : 0;
    __syncthreads();
    for (int off = 1; off < 512; off <<= 1) {
        int v = (t >= off) ? s[t - off] : 0;
        __syncthreads();
        s[t] += v;
        __syncthreads();
    }
    if (t < nb) partials[t] = (t == 0) ? 0 : s[t - 1];
}

__global__ void k_scan3(int* __restrict__ rowptr, const int* __restrict__ partials, int n) {
    int i = blockIdx.x * 256 + threadIdx.x;
    if (i < n) rowptr[i + 1] += partials[blockIdx.x];
    if (i == 0) rowptr[0] = 0;
}

// cursor pre-initialized to rowptr; dst-bucketed by blockIdx&7 (~XCD).
__global__ void k_fill(const int* __restrict__ src, const int* __restrict__ dst,
                       int* __restrict__ cursor, int* __restrict__ csr_src,
                       int E, int N) {
    int q  = blockIdx.x & 7;
    int r  = blockIdx.x >> 3;
    int nb = gridDim.x >> 3;
    int lo = (int)(((long long)q * N) / 8);
    int hi = (int)(((long long)(q + 1) * N) / 8);
    const int4v* d4 = (const int4v*)dst;
    const int4v* s4 = (const int4v*)src;
    int nv = E >> 2;
    for (int i = r * blockDim.x + threadIdx.x; i < nv; i += nb * blockDim.x) {
        int4v d = __builtin_nontemporal_load(&d4[i]);
        int4v s = __builtin_nontemporal_load(&s4[i]);
#pragma unroll
        for (int j = 0; j < 4; ++j) {
            int dd = d[j];
            if (dd >= lo && dd < hi) {
                int pos = atomicAdd(&cursor[dd], 1);
                csr_src[pos] = s[j];
            }
        }
    }
    if (r == 0) {
        for (int e = (nv << 2) + threadIdx.x; e < E; e += blockDim.x) {
            int dd = dst[e];
            if (dd >= lo && dd < hi) {
                int pos = atomicAdd(&cursor[dd], 1);
                csr_src[pos] = src[e];
            }
        }
    }
}

// ---- layer-1 GEMM: hps[n,32] = dis ⊙ (x[n,128] @ W[128,32]) ----
// 128 threads, 64 rows/block, register 4x4 tile, W+h staged in LDS.
__global__ void k_gemm1(const float* __restrict__ h, const float* __restrict__ W,
                        const float* __restrict__ dis, float* __restrict__ hps, int n) {
    __shared__ float sW[128 * 32];          // [k][col]
    __shared__ float sh[64 * 132];          // [row][k], pad 132
    int tid = threadIdx.x;
    int row0 = blockIdx.x * 64;
    for (int j = tid; j < 1024; j += 128)
        *(float4*)&sW[j * 4] = *(const float4*)&W[j * 4];
    for (int j = tid; j < 2048; j += 128) {
        int r = j >> 5, c4 = j & 31;
        float4v v = {0.f, 0.f, 0.f, 0.f};
        if (row0 + r < n)
            v = __builtin_nontemporal_load((const float4v*)&h[(size_t)(row0 + r) * 128 + c4 * 4]);
        *(float4v*)&sh[r * 132 + c4 * 4] = v;
    }
    __syncthreads();
    int rg = tid >> 3;      // 0..15 -> 4 rows each
    int cg = tid & 7;       // 0..7  -> 4 cols each
    float acc[4][4] = {};
    const float* shp = &sh[(rg * 4) * 132];
    const float* swp = &sW[cg * 4];
#pragma unroll 8
    for (int k4 = 0; k4 < 32; ++k4) {
        float4 hv[4], wv[4];
#pragma unroll
        for (int r = 0; r < 4; ++r) hv[r] = *(const float4*)&shp[r * 132 + k4 * 4];
#pragma unroll
        for (int t = 0; t < 4; ++t) wv[t] = *(const float4*)&swp[(k4 * 4 + t) * 32];
#pragma unroll
        for (int r = 0; r < 4; ++r) {
            const float hr[4] = {hv[r].x, hv[r].y, hv[r].z, hv[r].w};
#pragma unroll
            for (int t = 0; t < 4; ++t) {
                acc[r][0] += hr[t] * wv[t].x;
                acc[r][1] += hr[t] * wv[t].y;
                acc[r][2] += hr[t] * wv[t].z;
                acc[r][3] += hr[t] * wv[t].w;
            }
        }
    }
#pragma unroll
    for (int r = 0; r < 4; ++r) {
        int row = row0 + rg * 4 + r;
        if (row < n) {
            float dv = dis[row];
            float4 o = make_float4(acc[r][0] * dv, acc[r][1] * dv,
                                   acc[r][2] * dv, acc[r][3] * dv);
            *(float4*)&hps[(size_t)row * 32 + cg * 4] = o;
        }
    }
}

// ---- aggregation (+ optional fused next-layer GEMM epilogue) ----
// 32-lane group per node; coalesced 32-wide csr load + shfl broadcast gives
// up to 32 independent hps gathers in flight.
template <bool FUSE>
__global__ void k_agg(const float* __restrict__ hps, const int* __restrict__ rowptr,
                      const int* __restrict__ csr_src, const float* __restrict__ dis,
                      const float* __restrict__ bias, float* __restrict__ outc,
                      int n, const float* __restrict__ Wn, float* __restrict__ hpsn) {
    __shared__ float sW[32 * 32];
    if (FUSE) {
        for (int i = threadIdx.x; i < 1024; i += 256) sW[i] = Wn[i];
        __syncthreads();
    }
    int g    = (blockIdx.x * blockDim.x + threadIdx.x) >> 5;
    int lane = threadIdx.x & 31;
    if (g >= n) return;
    float acc = hps[(size_t)g * 32 + lane];   // self term
    int e0 = rowptr[g], e1 = rowptr[g + 1];
    int e = e0;
    while (e < e1) {
        int m = e1 - e; if (m > 32) m = 32;
        int sv = (e + lane < e1) ? __builtin_nontemporal_load(&csr_src[e + lane]) : 0;
        for (int k = 0; k < m; ++k) {
            int s = __shfl(sv, k, 32);
            acc += hps[(size_t)s * 32 + lane];
        }
        e += m;
    }
    float dg = dis[g];
    float v = tanhf(dg * acc + bias[lane]);
    __builtin_nontemporal_store(v, &outc[(size_t)g * 96 + lane]);
    if (FUSE) {
        float a2 = 0.0f;
#pragma unroll
        for (int k = 0; k < 32; ++k)
            a2 += __shfl(v, k, 32) * sW[k * 32 + lane];
        hpsn[(size_t)g * 32 + lane] = dg * a2;
    }
}

__global__ void k_idx(const int* __restrict__ batch, int* __restrict__ idx, int n, int g) {
    int i = blockIdx.x * blockDim.x + threadIdx.x;
    if (i >= g) return;
    int lo = 0, hi = n;
    while (lo < hi) {
        int mid = (lo + hi) >> 1;
        if (batch[mid] < i) lo = mid + 1; else hi = mid;
    }
    idx[i] = lo;
}

__global__ void k_head(const float* __restrict__ cat, const int* __restrict__ idx,
                       const float* __restrict__ w1, const float* __restrict__ b1,
                       const float* __restrict__ w2, const float* __restrict__ b2,
                       float* __restrict__ out) {
    __shared__ float gv[96];
    __shared__ float s0[128];
    __shared__ float s1[128];
    int g = blockIdx.x, t = threadIdx.x;
    int node = idx[g];
    if (t < 96) gv[t] = cat[(size_t)node * 96 + t];
    __syncthreads();
    float acc = b1[t];
#pragma unroll 8
    for (int i = 0; i < 96; ++i) acc += gv[i] * w1[i * 128 + t];
    float h = fmaxf(acc, 0.0f);
    s0[t] = h * w2[t * 2 + 0];
    s1[t] = h * w2[t * 2 + 1];
    __syncthreads();
    for (int off = 64; off > 0; off >>= 1) {
        if (t < off) { s0[t] += s0[t + off]; s1[t] += s1[t + off]; }
        __syncthreads();
    }
    if (t == 0) {
        float l0 = s0[0] + b2[0];
        float l1 = s1[0] + b2[1];
        float m  = fmaxf(l0, l1);
        float lse = m + logf(expf(l0 - m) + expf(l1 - m));
        out[(size_t)g * 2 + 0] = l0 - lse;
        out[(size_t)g * 2 + 1] = l1 - lse;
    }
}

extern "C" void kernel_launch(void* const* d_in, const int* in_sizes, int n_in,
                              void* d_out, int out_size, void* d_ws, size_t ws_size,
                              hipStream_t stream) {
    const float* x    = (const float*)d_in[0];
    const int*   ei   = (const int*)d_in[1];
    const int*   batch= (const int*)d_in[2];
    const float* W1   = (const float*)d_in[4];
    const float* b1   = (const float*)d_in[5];
    const float* W2   = (const float*)d_in[6];
    const float* b2   = (const float*)d_in[7];
    const float* W3   = (const float*)d_in[8];
    const float* b3   = (const float*)d_in[9];
    const float* l1w  = (const float*)d_in[10];
    const float* l1b  = (const float*)d_in[11];
    const float* l2w  = (const float*)d_in[12];
    const float* l2b  = (const float*)d_in[13];
    float* out = (float*)d_out;

    const int N = in_sizes[0] / 128;
    const int E = in_sizes[1] / 2;
    const int G = out_size / 2;
    const int* src = ei;
    const int* dst = ei + E;

    char* w = (char*)d_ws;
    auto alloc = [&](size_t bytes) {
        char* p = w;
        w += (bytes + 255) & ~(size_t)255;
        return p;
    };
    int*   cnt      = (int*)  alloc((size_t)N * 4);
    float* dis      = (float*)alloc((size_t)N * 4);
    int*   rowptr   = (int*)  alloc((size_t)(N + 1) * 4);
    int*   cursor   = (int*)  alloc((size_t)N * 4);
    int*   partials = (int*)  alloc(((size_t)(N + 255) / 256) * 4);
    int*   csr_src  = (int*)  alloc((size_t)E * 4);
    float* hpsA     = (float*)alloc((size_t)N * 32 * 4);
    float* hpsB     = (float*)alloc((size_t)N * 32 * 4);
    float* catb     = (float*)alloc((size_t)N * 96 * 4);
    int*   idx      = (int*)  alloc((size_t)G * 4);

    const int nb       = (N + 255) / 256;        // scan blocks
    const int nodes_bl = (N * 32 + 255) / 256;   // 8 nodes per 256-thr block
    const int gemm_bl  = (N + 63) / 64;
    const int bkt_bl   = 2048;                   // 256 blocks per dst bucket

    hipMemsetAsync(cnt, 0, (size_t)N * 4, stream);

    k_count<<<bkt_bl, 256, 0, stream>>>(dst, cnt, E, N);
    k_scan1<<<nb, 256, 0, stream>>>(cnt, rowptr, partials, dis, N);
    k_scan2<<<1, 512, 0, stream>>>(partials, nb);
    k_scan3<<<nb, 256, 0, stream>>>(rowptr, partials, N);
    hipMemcpyAsync(cursor, rowptr, (size_t)N * 4, hipMemcpyDeviceToDevice, stream);
    k_fill<<<bkt_bl, 256, 0, stream>>>(src, dst, cursor, csr_src, E, N);

    // layer 1 GEMM, then agg layers (2/3 GEMMs fused into agg epilogues)
    k_gemm1<<<gemm_bl, 128, 0, stream>>>(x, W1, dis, hpsA, N);
    k_agg<true ><<<nodes_bl, 256, 0, stream>>>(hpsA, rowptr, csr_src, dis, b1, catb + 0,  N, W2, hpsB);
    k_agg<true ><<<nodes_bl, 256, 0, stream>>>(hpsB, rowptr, csr_src, dis, b2, catb + 32, N, W3, hpsA);
    k_agg<false><<<nodes_bl, 256, 0, stream>>>(hpsA, rowptr, csr_src, dis, b3, catb + 64, N, nullptr, nullptr);

    k_idx<<<(G + 255) / 256, 256, 0, stream>>>(batch, idx, N, G);
    k_head<<<G, 128, 0, stream>>>(catb, idx, l1w, l1b, l2w, l2b, out);
}

// Round 6
// 351.822 us; speedup vs baseline: 1.4135x; 1.2114x over previous
//
#include <hip/hip_runtime.h>
#include <math.h>

// ---------------------------------------------------------------------------
// GCN: 3 layers (128->32->32->32), XCD-bucketed CSR build (nt streaming loads),
// fused agg+GEMM, readout + MLP head.
// Algebra: agg[g] = tanh( dis[g] * ( sum_{e:dst=g} hps[src_e] + hps[g] ) + b )
//          where hps = dis ⊙ (h @ W).
// k_agg edge loop is 8-way batched: 8 independent row-gathers in flight per
// 32-lane group (was 1 -> latency-bound, VGPR=12).
// ---------------------------------------------------------------------------

typedef int   int4v   __attribute__((ext_vector_type(4)));
typedef float float4v __attribute__((ext_vector_type(4)));

__global__ void k_count(const int* __restrict__ dst, int* __restrict__ cnt,
                        int E, int N) {
    int q  = blockIdx.x & 7;
    int r  = blockIdx.x >> 3;
    int nb = gridDim.x >> 3;
    int lo = (int)(((long long)q * N) / 8);
    int hi = (int)(((long long)(q + 1) * N) / 8);
    const int4v* d4 = (const int4v*)dst;
    int nv = E >> 2;
    for (int i = r * blockDim.x + threadIdx.x; i < nv; i += nb * blockDim.x) {
        int4v d = __builtin_nontemporal_load(&d4[i]);
#pragma unroll
        for (int j = 0; j < 4; ++j) {
            int dd = d[j];
            if (dd >= lo && dd < hi) atomicAdd(&cnt[dd], 1);
        }
    }
    if (r == 0) {
        for (int e = (nv << 2) + threadIdx.x; e < E; e += blockDim.x) {
            int dd = dst[e];
            if (dd >= lo && dd < hi) atomicAdd(&cnt[dd], 1);
        }
    }
}

// ---- scan (rowptr) + dis fused ----
__global__ void k_scan1(const int* __restrict__ cnt, int* __restrict__ rowptr,
                        int* __restrict__ partials, float* __restrict__ dis, int n) {
    __shared__ int s[256];
    int i = blockIdx.x * 256 + threadIdx.x;
    int v = (i < n) ? cnt[i] : 0;
    if (i < n) dis[i] = rsqrtf(1.0f + (float)v);
    s[threadIdx.x] = v;
    __syncthreads();
    for (int off = 1; off < 256; off <<= 1) {
        int t = (threadIdx.x >= off) ? s[threadIdx.x - off] : 0;
        __syncthreads();
        s[threadIdx.x] += t;
        __syncthreads();
    }
    if (i < n) rowptr[i + 1] = s[threadIdx.x];
    if (threadIdx.x == 255) partials[blockIdx.x] = s[255];
}

__global__ void k_scan2(int* __restrict__ partials, int nb) {
    __shared__ int s[512];
    int t = threadIdx.x;
    s[t] = (t < nb) ? partials[t] : 0;
    __syncthreads();
    for (int off = 1; off < 512; off <<= 1) {
        int v = (t >= off) ? s[t - off] : 0;
        __syncthreads();
        s[t] += v;
        __syncthreads();
    }
    if (t < nb) partials[t] = (t == 0) ? 0 : s[t - 1];
}

__global__ void k_scan3(int* __restrict__ rowptr, const int* __restrict__ partials, int n) {
    int i = blockIdx.x * 256 + threadIdx.x;
    if (i < n) rowptr[i + 1] += partials[blockIdx.x];
    if (i == 0) rowptr[0] = 0;
}

// cursor pre-initialized to rowptr; dst-bucketed by blockIdx&7 (~XCD).
__global__ void k_fill(const int* __restrict__ src, const int* __restrict__ dst,
                       int* __restrict__ cursor, int* __restrict__ csr_src,
                       int E, int N) {
    int q  = blockIdx.x & 7;
    int r  = blockIdx.x >> 3;
    int nb = gridDim.x >> 3;
    int lo = (int)(((long long)q * N) / 8);
    int hi = (int)(((long long)(q + 1) * N) / 8);
    const int4v* d4 = (const int4v*)dst;
    const int4v* s4 = (const int4v*)src;
    int nv = E >> 2;
    for (int i = r * blockDim.x + threadIdx.x; i < nv; i += nb * blockDim.x) {
        int4v d = __builtin_nontemporal_load(&d4[i]);
        int4v s = __builtin_nontemporal_load(&s4[i]);
#pragma unroll
        for (int j = 0; j < 4; ++j) {
            int dd = d[j];
            if (dd >= lo && dd < hi) {
                int pos = atomicAdd(&cursor[dd], 1);
                csr_src[pos] = s[j];
            }
        }
    }
    if (r == 0) {
        for (int e = (nv << 2) + threadIdx.x; e < E; e += blockDim.x) {
            int dd = dst[e];
            if (dd >= lo && dd < hi) {
                int pos = atomicAdd(&cursor[dd], 1);
                csr_src[pos] = src[e];
            }
        }
    }
}

// ---- layer-1 GEMM: hps[n,32] = dis ⊙ (x[n,128] @ W[128,32]) ----
__global__ void k_gemm1(const float* __restrict__ h, const float* __restrict__ W,
                        const float* __restrict__ dis, float* __restrict__ hps, int n) {
    __shared__ float sW[128 * 32];          // [k][col]
    __shared__ float sh[64 * 132];          // [row][k], pad 132
    int tid = threadIdx.x;
    int row0 = blockIdx.x * 64;
    for (int j = tid; j < 1024; j += 128)
        *(float4*)&sW[j * 4] = *(const float4*)&W[j * 4];
    for (int j = tid; j < 2048; j += 128) {
        int r = j >> 5, c4 = j & 31;
        float4v v = {0.f, 0.f, 0.f, 0.f};
        if (row0 + r < n)
            v = __builtin_nontemporal_load((const float4v*)&h[(size_t)(row0 + r) * 128 + c4 * 4]);
        *(float4v*)&sh[r * 132 + c4 * 4] = v;
    }
    __syncthreads();
    int rg = tid >> 3;      // 0..15 -> 4 rows each
    int cg = tid & 7;       // 0..7  -> 4 cols each
    float acc[4][4] = {};
    const float* shp = &sh[(rg * 4) * 132];
    const float* swp = &sW[cg * 4];
#pragma unroll 8
    for (int k4 = 0; k4 < 32; ++k4) {
        float4 hv[4], wv[4];
#pragma unroll
        for (int r = 0; r < 4; ++r) hv[r] = *(const float4*)&shp[r * 132 + k4 * 4];
#pragma unroll
        for (int t = 0; t < 4; ++t) wv[t] = *(const float4*)&swp[(k4 * 4 + t) * 32];
#pragma unroll
        for (int r = 0; r < 4; ++r) {
            const float hr[4] = {hv[r].x, hv[r].y, hv[r].z, hv[r].w};
#pragma unroll
            for (int t = 0; t < 4; ++t) {
                acc[r][0] += hr[t] * wv[t].x;
                acc[r][1] += hr[t] * wv[t].y;
                acc[r][2] += hr[t] * wv[t].z;
                acc[r][3] += hr[t] * wv[t].w;
            }
        }
    }
#pragma unroll
    for (int r = 0; r < 4; ++r) {
        int row = row0 + rg * 4 + r;
        if (row < n) {
            float dv = dis[row];
            float4 o = make_float4(acc[r][0] * dv, acc[r][1] * dv,
                                   acc[r][2] * dv, acc[r][3] * dv);
            *(float4*)&hps[(size_t)row * 32 + cg * 4] = o;
        }
    }
}

// ---- aggregation (+ optional fused next-layer GEMM epilogue) ----
// 32-lane group per node; 8-way batched gathers for memory-level parallelism.
template <bool FUSE>
__global__ void k_agg(const float* __restrict__ hps, const int* __restrict__ rowptr,
                      const int* __restrict__ csr_src, const float* __restrict__ dis,
                      const float* __restrict__ bias, float* __restrict__ outc,
                      int n, const float* __restrict__ Wn, float* __restrict__ hpsn) {
    __shared__ float sW[32 * 32];
    if (FUSE) {
        for (int i = threadIdx.x; i < 1024; i += 256) sW[i] = Wn[i];
        __syncthreads();
    }
    int g    = (blockIdx.x * blockDim.x + threadIdx.x) >> 5;
    int lane = threadIdx.x & 31;
    if (g >= n) return;
    float acc = hps[(size_t)g * 32 + lane];   // self term
    int e0 = rowptr[g], e1 = rowptr[g + 1];
    int e = e0;
    while (e < e1) {
        int m = e1 - e; if (m > 32) m = 32;
        int sv = (e + lane < e1) ? __builtin_nontemporal_load(&csr_src[e + lane]) : 0;
        int k = 0;
        for (; k + 8 <= m; k += 8) {
            float v[8];
#pragma unroll
            for (int j = 0; j < 8; ++j) {
                int s = __shfl(sv, k + j, 32);
                v[j] = hps[(size_t)s * 32 + lane];
            }
            acc += ((v[0] + v[1]) + (v[2] + v[3])) + ((v[4] + v[5]) + (v[6] + v[7]));
        }
        if (k + 4 <= m) {
            float v[4];
#pragma unroll
            for (int j = 0; j < 4; ++j) {
                int s = __shfl(sv, k + j, 32);
                v[j] = hps[(size_t)s * 32 + lane];
            }
            acc += (v[0] + v[1]) + (v[2] + v[3]);
            k += 4;
        }
        for (; k < m; ++k) {
            int s = __shfl(sv, k, 32);
            acc += hps[(size_t)s * 32 + lane];
        }
        e += m;
    }
    float dg = dis[g];
    float v = tanhf(dg * acc + bias[lane]);
    __builtin_nontemporal_store(v, &outc[(size_t)g * 96 + lane]);
    if (FUSE) {
        float a2 = 0.0f;
#pragma unroll
        for (int k = 0; k < 32; ++k)
            a2 += __shfl(v, k, 32) * sW[k * 32 + lane];
        hpsn[(size_t)g * 32 + lane] = dg * a2;
    }
}

__global__ void k_idx(const int* __restrict__ batch, int* __restrict__ idx, int n, int g) {
    int i = blockIdx.x * blockDim.x + threadIdx.x;
    if (i >= g) return;
    int lo = 0, hi = n;
    while (lo < hi) {
        int mid = (lo + hi) >> 1;
        if (batch[mid] < i) lo = mid + 1; else hi = mid;
    }
    idx[i] = lo;
}

__global__ void k_head(const float* __restrict__ cat, const int* __restrict__ idx,
                       const float* __restrict__ w1, const float* __restrict__ b1,
                       const float* __restrict__ w2, const float* __restrict__ b2,
                       float* __restrict__ out) {
    __shared__ float gv[96];
    __shared__ float s0[128];
    __shared__ float s1[128];
    int g = blockIdx.x, t = threadIdx.x;
    int node = idx[g];
    if (t < 96) gv[t] = cat[(size_t)node * 96 + t];
    __syncthreads();
    float acc = b1[t];
#pragma unroll 8
    for (int i = 0; i < 96; ++i) acc += gv[i] * w1[i * 128 + t];
    float h = fmaxf(acc, 0.0f);
    s0[t] = h * w2[t * 2 + 0];
    s1[t] = h * w2[t * 2 + 1];
    __syncthreads();
    for (int off = 64; off > 0; off >>= 1) {
        if (t < off) { s0[t] += s0[t + off]; s1[t] += s1[t + off]; }
        __syncthreads();
    }
    if (t == 0) {
        float l0 = s0[0] + b2[0];
        float l1 = s1[0] + b2[1];
        float m  = fmaxf(l0, l1);
        float lse = m + logf(expf(l0 - m) + expf(l1 - m));
        out[(size_t)g * 2 + 0] = l0 - lse;
        out[(size_t)g * 2 + 1] = l1 - lse;
    }
}

extern "C" void kernel_launch(void* const* d_in, const int* in_sizes, int n_in,
                              void* d_out, int out_size, void* d_ws, size_t ws_size,
                              hipStream_t stream) {
    const float* x    = (const float*)d_in[0];
    const int*   ei   = (const int*)d_in[1];
    const int*   batch= (const int*)d_in[2];
    const float* W1   = (const float*)d_in[4];
    const float* b1   = (const float*)d_in[5];
    const float* W2   = (const float*)d_in[6];
    const float* b2   = (const float*)d_in[7];
    const float* W3   = (const float*)d_in[8];
    const float* b3   = (const float*)d_in[9];
    const float* l1w  = (const float*)d_in[10];
    const float* l1b  = (const float*)d_in[11];
    const float* l2w  = (const float*)d_in[12];
    const float* l2b  = (const float*)d_in[13];
    float* out = (float*)d_out;

    const int N = in_sizes[0] / 128;
    const int E = in_sizes[1] / 2;
    const int G = out_size / 2;
    const int* src = ei;
    const int* dst = ei + E;

    char* w = (char*)d_ws;
    auto alloc = [&](size_t bytes) {
        char* p = w;
        w += (bytes + 255) & ~(size_t)255;
        return p;
    };
    int*   cnt      = (int*)  alloc((size_t)N * 4);
    float* dis      = (float*)alloc((size_t)N * 4);
    int*   rowptr   = (int*)  alloc((size_t)(N + 1) * 4);
    int*   cursor   = (int*)  alloc((size_t)N * 4);
    int*   partials = (int*)  alloc(((size_t)(N + 255) / 256) * 4);
    int*   csr_src  = (int*)  alloc((size_t)E * 4);
    float* hpsA     = (float*)alloc((size_t)N * 32 * 4);
    float* hpsB     = (float*)alloc((size_t)N * 32 * 4);
    float* catb     = (float*)alloc((size_t)N * 96 * 4);
    int*   idx      = (int*)  alloc((size_t)G * 4);

    const int nb       = (N + 255) / 256;        // scan blocks
    const int nodes_bl = (N * 32 + 255) / 256;   // 8 nodes per 256-thr block
    const int gemm_bl  = (N + 63) / 64;
    const int bkt_bl   = 2048;                   // 256 blocks per dst bucket

    hipMemsetAsync(cnt, 0, (size_t)N * 4, stream);

    k_count<<<bkt_bl, 256, 0, stream>>>(dst, cnt, E, N);
    k_scan1<<<nb, 256, 0, stream>>>(cnt, rowptr, partials, dis, N);
    k_scan2<<<1, 512, 0, stream>>>(partials, nb);
    k_scan3<<<nb, 256, 0, stream>>>(rowptr, partials, N);
    hipMemcpyAsync(cursor, rowptr, (size_t)N * 4, hipMemcpyDeviceToDevice, stream);
    k_fill<<<bkt_bl, 256, 0, stream>>>(src, dst, cursor, csr_src, E, N);

    // layer 1 GEMM, then agg layers (2/3 GEMMs fused into agg epilogues)
    k_gemm1<<<gemm_bl, 128, 0, stream>>>(x, W1, dis, hpsA, N);
    k_agg<true ><<<nodes_bl, 256, 0, stream>>>(hpsA, rowptr, csr_src, dis, b1, catb + 0,  N, W2, hpsB);
    k_agg<true ><<<nodes_bl, 256, 0, stream>>>(hpsB, rowptr, csr_src, dis, b2, catb + 32, N, W3, hpsA);
    k_agg<false><<<nodes_bl, 256, 0, stream>>>(hpsA, rowptr, csr_src, dis, b3, catb + 64, N, nullptr, nullptr);

    k_idx<<<(G + 255) / 256, 256, 0, stream>>>(batch, idx, N, G);
    k_head<<<G, 128, 0, stream>>>(catb, idx, l1w, l1b, l2w, l2b, out);
}